// Round 8
// baseline (18.392 us; speedup 1.0000x reference)
//
#include <hip/hip_runtime.h>

#define SDF_THR 5e-5f
#define TRACE_ITERS 10
#define N_STEPS 100
#define N_ROOTFIND 8
#define QGUARD 1e-5f

// raw v_sqrt_f32 (~1 ulp) — avoids the IEEE fixup sequence on the critical path
__device__ __forceinline__ float fast_sqrtf(float x) {
#if __has_builtin(__builtin_amdgcn_sqrtf)
    return __builtin_amdgcn_sqrtf(x);
#else
    return sqrtf(x);
#endif
}

// correctly-rounded k/99.0f (Markstein 2-fma refinement); constant-folds for literal k
__device__ __forceinline__ float div99(int k) {
    const float c = 1.0f / 99.0f;
    float fk = (float)k;
    float t0 = fk * c;
    float e  = fmaf(t0, -99.0f, fk);
    return fmaf(e, c, t0);
}

__device__ __forceinline__ float zq(int k, float dzr, float smin) {
    return fmaf(div99(k), dzr, smin);
}
__device__ __forceinline__ float qat(float z, float trcd, float cam2) {
    return fmaf(z, z + trcd, cam2);
}
// sdf(cam + a*ray) with |ray|=1:  q(a) = a^2 + 2a*rcd + cam2
__device__ __forceinline__ float sdfq(float a, float trcd, float cam2) {
    return fast_sqrtf(fmaxf(qat(a, trcd, cam2), 0.0f)) - 1.0f;
}

// 2 threads per ray: even lane = start-chain, odd lane = end-chain (sign = +1/-1).
// Doubles TLP (4 -> 8 waves/SIMD) and halves the per-wave dependent sqrt chain.
__global__ __launch_bounds__(256) void raytrace_lane2_kernel(
    const float* __restrict__ cam, const float* __restrict__ ray,
    float* __restrict__ out, int N, int nshift, int R)
{
    int t = blockIdx.x * blockDim.x + threadIdx.x;
    if (t >= 2 * R) return;
    int  gid  = t >> 1;
    bool is_s = (t & 1) == 0;
    float sign = is_s ? 1.0f : -1.0f;
    int b = (nshift >= 0) ? (gid >> nshift) : (gid / N);

    float cx = cam[b * 3 + 0], cy = cam[b * 3 + 1], cz = cam[b * 3 + 2];
    float rx = ray[(size_t)gid * 3 + 0], ry = ray[(size_t)gid * 3 + 1], rz = ray[(size_t)gid * 3 + 2];

    float rcd  = rx * cx + ry * cy + rz * cz;
    float cam2 = cx * cx + cy * cy + cz * cz;
    float trcd = rcd + rcd;

    // ---- sphere intersections (OBJ_R = 5); one-time sqrt kept correctly rounded ----
    float under = rcd * rcd - (cam2 - 25.0f);
    bool  m0 = under > 0.0f;
    float sq = sqrtf(m0 ? under : 1.0f);
    float start = is_s ? fmaxf(-sq - rcd, 0.0f) : fmaxf(sq - rcd, 0.0f);

    bool  unf = m0;
    float acc = m0 ? start : 0.0f;
    // unconditional next is decision-safe: dead lanes have cur==0 -> acc frozen
    float next = sdfq(acc, trcd, cam2);

    #pragma unroll 1
    for (int i = 0; i < TRACE_ITERS; ++i) {
        float cur = (unf && next > SDF_THR) ? next : 0.0f;
        unf = unf && (cur > SDF_THR);
        acc = fmaf(sign, cur, acc);            // exact: sign in {+1,-1}
        next = sdfq(acc, trcd, cam2);
        float scos = sign * (rcd + acc);       // s: cos>0 ; e: cos<0
        bool np = (next < 0.0f) || (scos > 0.0f);
        float st  = 0.9f * cur;
        float acc2  = acc - sign * st;         // s: acc-0.9cur ; e: acc+0.9cur
        float next2 = sdfq(acc2, trcd, cam2);
        acc  = np ? acc2  : acc;
        next = np ? next2 : next;
        float other = __shfl_xor(acc, 1);      // partner chain's acc
        float a_s = is_s ? acc : other;
        float a_e = is_s ? other : acc;
        unf = unf && (a_s < a_e);
        if (!__any(unf)) break;                // bit-exact: converged lanes are no-ops
    }

    float acc_other = __shfl_xor(acc, 1);      // all lanes active here

    if (is_s) {
        float acc_s = acc, acc_e = acc_other;
        // final mask refresh
        bool unf_s = unf && (next > SDF_THR);

        bool  out_m = acc_s < acc_e;
        float out_d = acc_s;

        if (unf_s) {
            // ---- analytic sampler (round-7, verbatim): decisions on q(z) vs 1 ----
            float smin = acc_s, dzr = acc_e - acc_s;
            float step99 = dzr * (1.0f / 99.0f);
            bool fellback = false;

            // (a) discrete argmin + any-negative: window around the parabola vertex
            float fkv = (-rcd - smin) / step99;
            fkv = fminf(fmaxf(fkv, 0.0f), 99.0f);
            int kv = (int)fkv;
            float bq = 3.4e38f; float bkf = 0.0f;
            #pragma unroll
            for (int d = -2; d <= 3; ++d) {
                int k = min(max(kv + d, 0), 99);
                float q = qat(zq(k, dzr, smin), trcd, cam2);
                bool better = q < bq;
                bq  = better ? q : bq;
                bkf = better ? (float)k : bkf;
            }

            if (fabsf(bq - 1.0f) <= QGUARD) {
                fellback = true;
            } else if (bq > 1.0f) {
                out_d = zq((int)bkf, dzr, smin);
                out_m = false;
            } else {
                int kneg = 1000;
                float q0 = qat(smin, trcd, cam2);
                if (q0 < 1.0f) {
                    kneg = 0;
                } else {
                    float disc = fmaf(rcd, rcd, 1.0f - cam2);
                    float zroot = -rcd - sqrtf(fmaxf(disc, 0.0f));
                    float fk = (zroot - smin) / step99;
                    fk = fminf(fmaxf(fk, -8.0f), 108.0f);
                    int ka = (int)ceilf(fk);
                    #pragma unroll
                    for (int d = -3; d <= 3; ++d) {
                        int k = min(max(ka + d, 1), 99);
                        float q = qat(zq(k, dzr, smin), trcd, cam2);
                        kneg = (q < 1.0f) ? min(kneg, k) : kneg;
                    }
                    if (kneg == 1000) {
                        fellback = true;
                    } else {
                        float qprev = qat(zq(kneg - 1, dzr, smin), trcd, cam2);
                        if (!(qprev >= 1.0f + QGUARD)) fellback = true;
                    }
                }
                if (!fellback) {
                    int klo = max(kneg - 1, 0);
                    float lo = zq(klo, dzr, smin);
                    float hi = zq(kneg, dzr, smin);
                    #pragma unroll
                    for (int it = 0; it < N_ROOTFIND; ++it) {
                        float mid = 0.5f * (lo + hi);
                        float qm  = qat(mid, trcd, cam2);
                        bool go_lo = qm > 1.0f;
                        lo = go_lo ? mid : lo;
                        hi = go_lo ? hi : mid;
                    }
                    out_d = 0.5f * (lo + hi);
                    out_m = true;
                }
            }

            if (fellback) {
                // bit-exact full scan (round-5 sampler, verbatim)
                float qmin[4] = {3.4e38f, 3.4e38f, 3.4e38f, 3.4e38f};
                float fkq[4]  = {0.0f, 0.0f, 0.0f, 0.0f};
                float fneg[4] = {1e9f, 1e9f, 1e9f, 1e9f};
                #pragma unroll
                for (int k = 0; k < N_STEPS; ++k) {
                    int j = k & 3;
                    float z = zq(k, dzr, smin);
                    float q = qat(z, trcd, cam2);
                    float fk = (float)k;
                    fneg[j] = fminf(fneg[j], (q < 1.0f) ? fk : 1e9f);
                    if (q < qmin[j]) { qmin[j] = q; fkq[j] = fk; }
                }
                float kneg_f = fminf(fminf(fneg[0], fneg[1]), fminf(fneg[2], fneg[3]));
                float bq2 = qmin[0], bk2 = fkq[0];
                #pragma unroll
                for (int j = 1; j < 4; ++j) {
                    bool better = (qmin[j] < bq2) || ((qmin[j] == bq2) && (fkq[j] < bk2));
                    bq2 = better ? qmin[j] : bq2;
                    bk2 = better ? fkq[j]  : bk2;
                }
                if (kneg_f < 1e8f) {
                    int kneg = (int)kneg_f;
                    int klo  = (kneg - 1 > 0) ? (kneg - 1) : 0;
                    float lo = zq(klo,  dzr, smin);
                    float hi = zq(kneg, dzr, smin);
                    #pragma unroll
                    for (int it = 0; it < N_ROOTFIND; ++it) {
                        float mid = 0.5f * (lo + hi);
                        float qm  = qat(mid, trcd, cam2);
                        bool go_lo = qm > 1.0f;
                        lo = go_lo ? mid : lo;
                        hi = go_lo ? hi : mid;
                    }
                    out_d = 0.5f * (lo + hi);
                    out_m = true;
                } else {
                    out_d = zq((int)bk2, dzr, smin);
                    out_m = false;
                }
            }
        }

        // ---- outputs: pts [R,3] | net_obj [R] | acc_s [R] ----
        out[(size_t)gid * 3 + 0] = fmaf(out_d, rx, cx);
        out[(size_t)gid * 3 + 1] = fmaf(out_d, ry, cy);
        out[(size_t)gid * 3 + 2] = fmaf(out_d, rz, cz);
        out[(size_t)R * 3 + gid] = out_m ? 1.0f : 0.0f;
        out[(size_t)R * 4 + gid] = out_d;
    }
}

extern "C" void kernel_launch(void* const* d_in, const int* in_sizes, int n_in,
                              void* d_out, int out_size, void* d_ws, size_t ws_size,
                              hipStream_t stream) {
    const float* cam = (const float*)d_in[0];
    const float* ray = (const float*)d_in[1];
    int B = in_sizes[0] / 3;
    int R = in_sizes[1] / 3;
    int N = R / B;
    int nshift = -1;
    if ((N & (N - 1)) == 0) { nshift = 0; while ((1 << nshift) != N) ++nshift; }
    int threads = 256;
    int total = 2 * R;
    int blocks = (total + threads - 1) / threads;
    raytrace_lane2_kernel<<<blocks, threads, 0, stream>>>(cam, ray, (float*)d_out,
                                                          N, nshift, R);
}

// Round 9
// 15.077 us; speedup vs baseline: 1.2199x; 1.2199x over previous
//
#include <hip/hip_runtime.h>

#define SDF_THR 5e-5f
#define TRACE_ITERS 10
#define N_STEPS 100
#define N_ROOTFIND 8
#define QGUARD 1e-5f

// raw v_sqrt_f32 (~1 ulp) — avoids the IEEE fixup sequence on the critical path
__device__ __forceinline__ float fast_sqrtf(float x) {
#if __has_builtin(__builtin_amdgcn_sqrtf)
    return __builtin_amdgcn_sqrtf(x);
#else
    return sqrtf(x);
#endif
}

// correctly-rounded k/99.0f (Markstein 2-fma refinement); same bits whether
// constant-folded (literal k) or evaluated at runtime.
__device__ __forceinline__ float div99(int k) {
    const float c = 1.0f / 99.0f;
    float fk = (float)k;
    float t0 = fk * c;
    float e  = fmaf(t0, -99.0f, fk);
    return fmaf(e, c, t0);
}

__device__ __forceinline__ float zq(int k, float dzr, float smin) {
    return fmaf(div99(k), dzr, smin);
}
__device__ __forceinline__ float qat(float z, float trcd, float cam2) {
    return fmaf(z, z + trcd, cam2);
}
// sdf(cam + a*ray) with |ray|=1:  q(a) = a^2 + 2a*rcd + cam2
__device__ __forceinline__ float sdfq(float a, float trcd, float cam2) {
    return fast_sqrtf(fmaxf(qat(a, trcd, cam2), 0.0f)) - 1.0f;
}

// 1 wave per block: per-wave retire granularity (tail imbalance fix).
__global__ __launch_bounds__(64) void raytrace_kernel(
    const float* __restrict__ cam, const float* __restrict__ ray,
    float* __restrict__ out, int N, int nshift, int R)
{
    int tid = blockIdx.x * 64 + threadIdx.x;
    bool alive = tid < R;
    int gid = alive ? tid : (R - 1);       // clamp; all 64 lanes stay live for coop ops
    int lane = threadIdx.x & 63;
    int b = (nshift >= 0) ? (gid >> nshift) : (gid / N);

    float cx = cam[b * 3 + 0], cy = cam[b * 3 + 1], cz = cam[b * 3 + 2];
    float rx = ray[(size_t)gid * 3 + 0], ry = ray[(size_t)gid * 3 + 1], rz = ray[(size_t)gid * 3 + 2];

    float rcd  = rx * cx + ry * cy + rz * cz;
    float cam2 = cx * cx + cy * cy + cz * cz;
    float trcd = rcd + rcd;

    // ---- sphere intersections (OBJ_R = 5); one-time sqrt kept correctly rounded ----
    float under = rcd * rcd - (cam2 - 25.0f);
    bool  m0 = under > 0.0f;
    float sq = sqrtf(m0 ? under : 1.0f);
    float nearv = m0 ? fmaxf(-sq - rcd, 0.0f) : 0.0f;
    float farv  = m0 ? fmaxf( sq - rcd, 0.0f) : 0.0f;

    // ---- sphere tracing (round-5/7 proven form, verbatim) ----
    bool  unf_s = m0, unf_e = m0;
    float acc_s = nearv, acc_e = farv;
    float next_s = unf_s ? sdfq(acc_s, trcd, cam2) : 0.0f;
    float next_e = unf_e ? sdfq(acc_e, trcd, cam2) : 0.0f;

    #pragma unroll 1
    for (int i = 0; i < TRACE_ITERS; ++i) {
        float cur_s = unf_s ? next_s : 0.0f;
        cur_s = (cur_s <= SDF_THR) ? 0.0f : cur_s;
        float cur_e = unf_e ? next_e : 0.0f;
        cur_e = (cur_e <= SDF_THR) ? 0.0f : cur_e;
        unf_s = unf_s && (cur_s > SDF_THR);
        unf_e = unf_e && (cur_e > SDF_THR);
        acc_s += cur_s;
        acc_e -= cur_e;
        next_s = unf_s ? sdfq(acc_s, trcd, cam2) : 0.0f;
        next_e = unf_e ? sdfq(acc_e, trcd, cam2) : 0.0f;
        bool np_s = (next_s < 0.0f) || (rcd + acc_s > 0.0f);   // ray.pts = rcd + acc
        bool np_e = (next_e < 0.0f) || (rcd + acc_e < 0.0f);
        if (np_s) { acc_s -= 0.9f * cur_s; next_s = sdfq(acc_s, trcd, cam2); }
        if (np_e) { acc_e += 0.9f * cur_e; next_e = sdfq(acc_e, trcd, cam2); }
        unf_s = unf_s && (acc_s < acc_e);
        unf_e = unf_e && (acc_s < acc_e);
        if (!__any(unf_s || unf_e)) break;   // bit-exact: converged lanes are no-ops
    }
    // final mask refresh
    {
        float cur_s = unf_s ? next_s : 0.0f;
        cur_s = (cur_s <= SDF_THR) ? 0.0f : cur_s;
        unf_s = unf_s && (cur_s > SDF_THR);
    }

    // ---- defaults from trace ----
    bool  out_m = acc_s < acc_e;
    float out_d = acc_s;

    float smin = acc_s, dzr = acc_e - acc_s;   // only consumed under unf_s / as fb source
    int   dec = 1;            // 1 = no-negative (use bk_nonneg), 2 = negative (use kneg), 0 = fallback
    int   kneg = 1000;
    float bk_nonneg = 0.0f;

    if (unf_s) {
        // ---- analytic sampler: all decisions on computed q(z_k) vs 1 ----
        float step99 = dzr * (1.0f / 99.0f);

        // (a) discrete argmin + any-negative: window around the parabola vertex
        float fkv = (-rcd - smin) / step99;
        fkv = fminf(fmaxf(fkv, 0.0f), 99.0f);
        int kv = (int)fkv;
        float bq = 3.4e38f; float bkf = 0.0f;
        #pragma unroll
        for (int d = -2; d <= 3; ++d) {
            int k = min(max(kv + d, 0), 99);
            float q = qat(zq(k, dzr, smin), trcd, cam2);
            bool better = q < bq;               // strict -> first occurrence
            bq  = better ? q : bq;
            bkf = better ? (float)k : bkf;
        }

        if (fabsf(bq - 1.0f) <= QGUARD) {
            dec = 0;                            // decision inside guard band
        } else if (bq > 1.0f) {
            dec = 1; bk_nonneg = bkf;           // no negative sample anywhere
        } else {
            float q0 = qat(smin, trcd, cam2);   // z_0 == smin exactly
            if (q0 < 1.0f) {
                dec = 2; kneg = 0;
            } else {
                float disc = fmaf(rcd, rcd, 1.0f - cam2);
                float zroot = -rcd - sqrtf(fmaxf(disc, 0.0f));   // left root of q=1
                float fk = (zroot - smin) / step99;
                fk = fminf(fmaxf(fk, -8.0f), 108.0f);
                int ka = (int)ceilf(fk);
                int kw = 1000;
                #pragma unroll
                for (int d = -3; d <= 3; ++d) {
                    int k = min(max(ka + d, 1), 99);
                    float q = qat(zq(k, dzr, smin), trcd, cam2);
                    kw = (q < 1.0f) ? min(kw, k) : kw;
                }
                if (kw == 1000) {
                    dec = 0;                    // analytic index off -> fallback
                } else {
                    float qprev = qat(zq(kw - 1, dzr, smin), trcd, cam2);
                    if (!(qprev >= 1.0f + QGUARD)) dec = 0;   // contiguity unproven
                    else { dec = 2; kneg = kw; }
                }
            }
        }
    }

    // ---- wave-cooperative fallback: full 100-sample scan as a 64-lane reduction.
    // Identical computed q at identical z_k; min-k / lex-min reductions reproduce
    // the sequential scan's first-occurrence semantics exactly.
    bool need_fb = unf_s && (dec == 0) && alive;
    unsigned long long fbm = __ballot(need_fb);
    while (fbm) {
        int src = __ffsll((unsigned long long)fbm) - 1;
        fbm &= fbm - 1;
        float s_smin = __shfl(smin, src);
        float s_dzr  = __shfl(dzr,  src);
        float s_trcd = __shfl(trcd, src);
        float s_cam2 = __shfl(cam2, src);
        // each lane evaluates k = lane and k = lane + 64 (if < 100)
        float q1 = qat(zq(lane, s_dzr, s_smin), s_trcd, s_cam2);
        int   k2 = lane + 64;
        bool  v2 = k2 < N_STEPS;
        float q2 = v2 ? qat(zq(k2, s_dzr, s_smin), s_trcd, s_cam2) : 3.4e38f;
        bool b2 = q2 < q1;                      // strict: tie keeps smaller k
        float mq = b2 ? q2 : q1;
        int   mk = b2 ? k2 : lane;
        int nk = 1000;
        nk = (q1 < 1.0f) ? lane : nk;
        nk = (v2 && q2 < 1.0f) ? min(nk, k2) : nk;
        #pragma unroll
        for (int off = 1; off < 64; off <<= 1) {
            float oq = __shfl_xor(mq, off);
            int   ok = __shfl_xor(mk, off);
            int   on = __shfl_xor(nk, off);
            bool bet = (oq < mq) || ((oq == mq) && (ok < mk));
            mq = bet ? oq : mq;
            mk = bet ? ok : mk;
            nk = min(nk, on);
        }
        if (lane == src) {
            if (nk < 1000) { dec = 2; kneg = nk; }
            else           { dec = 1; bk_nonneg = (float)mk; }
        }
    }

    // ---- final resolution (shared bisection for every kneg producer) ----
    if (unf_s) {
        if (dec == 2) {
            int klo = max(kneg - 1, 0);
            float lo = zq(klo,  dzr, smin);     // kneg==0 -> lo==hi==z0 (matches ref)
            float hi = zq(kneg, dzr, smin);
            #pragma unroll
            for (int it = 0; it < N_ROOTFIND; ++it) {
                float mid = 0.5f * (lo + hi);
                float qm  = qat(mid, trcd, cam2);
                bool go_lo = qm > 1.0f;         // sdf(mid) > 0
                lo = go_lo ? mid : lo;
                hi = go_lo ? hi : mid;
            }
            out_d = 0.5f * (lo + hi);
            out_m = true;
        } else {
            out_d = zq((int)bk_nonneg, dzr, smin);   // min-sdf sample
            out_m = false;
        }
    }

    // ---- outputs: pts [R,3] | net_obj [R] | acc_s [R] ----
    if (alive) {
        out[(size_t)gid * 3 + 0] = fmaf(out_d, rx, cx);
        out[(size_t)gid * 3 + 1] = fmaf(out_d, ry, cy);
        out[(size_t)gid * 3 + 2] = fmaf(out_d, rz, cz);
        out[(size_t)R * 3 + gid] = out_m ? 1.0f : 0.0f;
        out[(size_t)R * 4 + gid] = out_d;
    }
}

extern "C" void kernel_launch(void* const* d_in, const int* in_sizes, int n_in,
                              void* d_out, int out_size, void* d_ws, size_t ws_size,
                              hipStream_t stream) {
    const float* cam = (const float*)d_in[0];
    const float* ray = (const float*)d_in[1];
    int B = in_sizes[0] / 3;
    int R = in_sizes[1] / 3;
    int N = R / B;
    int nshift = -1;
    if ((N & (N - 1)) == 0) { nshift = 0; while ((1 << nshift) != N) ++nshift; }
    int threads = 64;
    int blocks = (R + threads - 1) / threads;
    raytrace_kernel<<<blocks, threads, 0, stream>>>(cam, ray, (float*)d_out, N, nshift, R);
}

// Round 10
// 13.372 us; speedup vs baseline: 1.3754x; 1.1275x over previous
//
#include <hip/hip_runtime.h>

#define SDF_THR 5e-5f
#define TRACE_ITERS 10
#define N_STEPS 100
#define N_ROOTFIND 8
#define QGUARD 1e-5f

// raw v_sqrt_f32 (~1 ulp) — avoids the IEEE fixup sequence on the critical path
__device__ __forceinline__ float fast_sqrtf(float x) {
#if __has_builtin(__builtin_amdgcn_sqrtf)
    return __builtin_amdgcn_sqrtf(x);
#else
    return sqrtf(x);
#endif
}

// correctly-rounded k/99.0f (Markstein 2-fma refinement); same bits whether
// constant-folded (literal k) or evaluated at runtime.
__device__ __forceinline__ float div99(int k) {
    const float c = 1.0f / 99.0f;
    float fk = (float)k;
    float t0 = fk * c;
    float e  = fmaf(t0, -99.0f, fk);
    return fmaf(e, c, t0);
}

__device__ __forceinline__ float zq(int k, float dzr, float smin) {
    return fmaf(div99(k), dzr, smin);
}
__device__ __forceinline__ float qat(float z, float trcd, float cam2) {
    return fmaf(z, z + trcd, cam2);
}
// sdf(cam + a*ray) with |ray|=1:  q(a) = a^2 + 2a*rcd + cam2
__device__ __forceinline__ float sdfq(float a, float trcd, float cam2) {
    return fast_sqrtf(fmaxf(qat(a, trcd, cam2), 0.0f)) - 1.0f;
}

// 1 wave per block. Trace loop: s-chain and e-chain fully DECOUPLED (no
// cross-compare feedback); joint freeze state latched off-chain. Proven
// equivalent: acc_s nondecreasing, acc_e nonincreasing, compare-failure
// freezes both chains (cur=0 => acc frozen; line-search no-op), so the joint
// trajectory equals the independent ones truncated at the first crossing.
__global__ __launch_bounds__(64) void raytrace_kernel(
    const float* __restrict__ cam, const float* __restrict__ ray,
    float* __restrict__ out, int N, int nshift, int R)
{
    int tid = blockIdx.x * 64 + threadIdx.x;
    bool aliveLane = tid < R;
    int gid = aliveLane ? tid : (R - 1);   // clamp; all 64 lanes live for coop ops
    int lane = threadIdx.x & 63;
    int b = (nshift >= 0) ? (gid >> nshift) : (gid / N);

    float cx = cam[b * 3 + 0], cy = cam[b * 3 + 1], cz = cam[b * 3 + 2];
    float rx = ray[(size_t)gid * 3 + 0], ry = ray[(size_t)gid * 3 + 1], rz = ray[(size_t)gid * 3 + 2];

    float rcd  = rx * cx + ry * cy + rz * cz;
    float cam2 = cx * cx + cy * cy + cz * cz;
    float trcd = rcd + rcd;

    // ---- sphere intersections (OBJ_R = 5); one-time sqrt kept correctly rounded ----
    float under = rcd * rcd - (cam2 - 25.0f);
    bool  m0 = under > 0.0f;
    float sq = sqrtf(m0 ? under : 1.0f);
    float nearv = m0 ? fmaxf(-sq - rcd, 0.0f) : 0.0f;
    float farv  = m0 ? fmaxf( sq - rcd, 0.0f) : 0.0f;

    // ---- decoupled sphere tracing ----
    bool  us = m0, ue = m0;                 // independent convergence flags
    float as = nearv, ae = farv;
    float ns = us ? sdfq(as, trcd, cam2) : 0.0f;
    float ne = ue ? sdfq(ae, trcd, cam2) : 0.0f;

    bool  alive = true;                     // joint not-yet-crossed
    float fs = as, fe = ae, fns = ns;       // latched joint state
    bool  ufs = us;

    #pragma unroll 1
    for (int i = 0; i < TRACE_ITERS; ++i) {
        // s-chain (independent)
        float cs = (us && ns > SDF_THR) ? ns : 0.0f;
        us = us && (ns > SDF_THR);
        as += cs;
        ns = sdfq(as, trcd, cam2);
        bool nps = (ns < 0.0f) || (rcd + as > 0.0f);
        float as2 = as - 0.9f * cs;
        float ns2 = sdfq(as2, trcd, cam2);  // == ns when cs==0 (bit-idempotent)
        as = nps ? as2 : as;
        ns = nps ? ns2 : ns;
        // e-chain (independent)
        float ce = (ue && ne > SDF_THR) ? ne : 0.0f;
        ue = ue && (ne > SDF_THR);
        ae -= ce;
        ne = sdfq(ae, trcd, cam2);
        bool npe = (ne < 0.0f) || (rcd + ae < 0.0f);
        float ae2 = ae + 0.9f * ce;
        float ne2 = sdfq(ae2, trcd, cam2);
        ae = npe ? ae2 : ae;
        ne = npe ? ne2 : ne;
        // joint latch (off-chain, no feedback into the recurrences)
        fs  = alive ? as : fs;
        fe  = alive ? ae : fe;
        fns = alive ? ns : fns;
        ufs = alive ? us : ufs;
        alive = alive && (as < ae);
        // lane done when crossed (frozen) or both chains converged (frozen)
        bool notdone = alive && (us || ue);
        if (!__any(notdone)) break;         // bit-exact: frozen lanes are no-ops
    }

    // joint final state
    bool unf_s = alive && ufs;
    // final mask refresh
    {
        float curf = unf_s ? fns : 0.0f;
        curf = (curf <= SDF_THR) ? 0.0f : curf;
        unf_s = unf_s && (curf > SDF_THR);
    }

    // ---- defaults from trace ----
    bool  out_m = fs < fe;
    float out_d = fs;

    float smin = fs, dzr = fe - fs;
    int   dec = 1;            // 1 = no-negative (bk_nonneg), 2 = negative (kneg), 0 = fallback
    int   kneg = 1000;
    float bk_nonneg = 0.0f;

    if (unf_s) {
        // ---- analytic sampler: all decisions on computed q(z_k) vs 1 ----
        float step99 = dzr * (1.0f / 99.0f);

        // (a) discrete argmin + any-negative: window around the parabola vertex
        float fkv = (-rcd - smin) / step99;
        fkv = fminf(fmaxf(fkv, 0.0f), 99.0f);
        int kv = (int)fkv;
        float bq = 3.4e38f; float bkf = 0.0f;
        #pragma unroll
        for (int d = -2; d <= 3; ++d) {
            int k = min(max(kv + d, 0), 99);
            float q = qat(zq(k, dzr, smin), trcd, cam2);
            bool better = q < bq;               // strict -> first occurrence
            bq  = better ? q : bq;
            bkf = better ? (float)k : bkf;
        }

        if (fabsf(bq - 1.0f) <= QGUARD) {
            dec = 0;                            // decision inside guard band
        } else if (bq > 1.0f) {
            dec = 1; bk_nonneg = bkf;           // no negative sample anywhere
        } else {
            float q0 = qat(smin, trcd, cam2);   // z_0 == smin exactly
            if (q0 < 1.0f) {
                dec = 2; kneg = 0;
            } else {
                float disc = fmaf(rcd, rcd, 1.0f - cam2);
                float zroot = -rcd - sqrtf(fmaxf(disc, 0.0f));   // left root of q=1
                float fk = (zroot - smin) / step99;
                fk = fminf(fmaxf(fk, -8.0f), 108.0f);
                int ka = (int)ceilf(fk);
                int kw = 1000;
                #pragma unroll
                for (int d = -3; d <= 3; ++d) {
                    int k = min(max(ka + d, 1), 99);
                    float q = qat(zq(k, dzr, smin), trcd, cam2);
                    kw = (q < 1.0f) ? min(kw, k) : kw;
                }
                if (kw == 1000) {
                    dec = 0;                    // analytic index off -> fallback
                } else {
                    float qprev = qat(zq(kw - 1, dzr, smin), trcd, cam2);
                    if (!(qprev >= 1.0f + QGUARD)) dec = 0;   // contiguity unproven
                    else { dec = 2; kneg = kw; }
                }
            }
        }
    }

    // ---- wave-cooperative fallback: full 100-sample scan as a 64-lane reduction ----
    bool need_fb = unf_s && (dec == 0) && aliveLane;
    unsigned long long fbm = __ballot(need_fb);
    while (fbm) {
        int src = __ffsll((unsigned long long)fbm) - 1;
        fbm &= fbm - 1;
        float s_smin = __shfl(smin, src);
        float s_dzr  = __shfl(dzr,  src);
        float s_trcd = __shfl(trcd, src);
        float s_cam2 = __shfl(cam2, src);
        float q1 = qat(zq(lane, s_dzr, s_smin), s_trcd, s_cam2);
        int   k2 = lane + 64;
        bool  v2 = k2 < N_STEPS;
        float q2 = v2 ? qat(zq(k2, s_dzr, s_smin), s_trcd, s_cam2) : 3.4e38f;
        bool b2 = q2 < q1;                      // strict: tie keeps smaller k
        float mq = b2 ? q2 : q1;
        int   mk = b2 ? k2 : lane;
        int nk = 1000;
        nk = (q1 < 1.0f) ? lane : nk;
        nk = (v2 && q2 < 1.0f) ? min(nk, k2) : nk;
        #pragma unroll
        for (int off = 1; off < 64; off <<= 1) {
            float oq = __shfl_xor(mq, off);
            int   ok = __shfl_xor(mk, off);
            int   on = __shfl_xor(nk, off);
            bool bet = (oq < mq) || ((oq == mq) && (ok < mk));
            mq = bet ? oq : mq;
            mk = bet ? ok : mk;
            nk = min(nk, on);
        }
        if (lane == src) {
            if (nk < 1000) { dec = 2; kneg = nk; }
            else           { dec = 1; bk_nonneg = (float)mk; }
        }
    }

    // ---- final resolution (shared bisection for every kneg producer) ----
    if (unf_s) {
        if (dec == 2) {
            int klo = max(kneg - 1, 0);
            float lo = zq(klo,  dzr, smin);     // kneg==0 -> lo==hi==z0 (matches ref)
            float hi = zq(kneg, dzr, smin);
            #pragma unroll
            for (int it = 0; it < N_ROOTFIND; ++it) {
                float mid = 0.5f * (lo + hi);
                float qm  = qat(mid, trcd, cam2);
                bool go_lo = qm > 1.0f;         // sdf(mid) > 0
                lo = go_lo ? mid : lo;
                hi = go_lo ? hi : mid;
            }
            out_d = 0.5f * (lo + hi);
            out_m = true;
        } else {
            out_d = zq((int)bk_nonneg, dzr, smin);   // min-sdf sample
            out_m = false;
        }
    }

    // ---- outputs: pts [R,3] | net_obj [R] | acc_s [R] ----
    if (aliveLane) {
        out[(size_t)gid * 3 + 0] = fmaf(out_d, rx, cx);
        out[(size_t)gid * 3 + 1] = fmaf(out_d, ry, cy);
        out[(size_t)gid * 3 + 2] = fmaf(out_d, rz, cz);
        out[(size_t)R * 3 + gid] = out_m ? 1.0f : 0.0f;
        out[(size_t)R * 4 + gid] = out_d;
    }
}

extern "C" void kernel_launch(void* const* d_in, const int* in_sizes, int n_in,
                              void* d_out, int out_size, void* d_ws, size_t ws_size,
                              hipStream_t stream) {
    const float* cam = (const float*)d_in[0];
    const float* ray = (const float*)d_in[1];
    int B = in_sizes[0] / 3;
    int R = in_sizes[1] / 3;
    int N = R / B;
    int nshift = -1;
    if ((N & (N - 1)) == 0) { nshift = 0; while ((1 << nshift) != N) ++nshift; }
    int threads = 64;
    int blocks = (R + threads - 1) / threads;
    raytrace_kernel<<<blocks, threads, 0, stream>>>(cam, ray, (float*)d_out, N, nshift, R);
}

// Round 11
// 13.225 us; speedup vs baseline: 1.3907x; 1.0111x over previous
//
#include <hip/hip_runtime.h>

#define SDF_THR 5e-5f
#define TRACE_ITERS 10
#define N_STEPS 100
#define N_ROOTFIND 8
#define QGUARD 1e-5f

// raw v_sqrt_f32 (~1 ulp) — avoids the IEEE fixup sequence on the critical path
__device__ __forceinline__ float fast_sqrtf(float x) {
#if __has_builtin(__builtin_amdgcn_sqrtf)
    return __builtin_amdgcn_sqrtf(x);
#else
    return sqrtf(x);
#endif
}

// correctly-rounded k/99.0f (Markstein 2-fma refinement); same bits whether
// constant-folded (literal k) or evaluated at runtime.
__device__ __forceinline__ float div99(int k) {
    const float c = 1.0f / 99.0f;
    float fk = (float)k;
    float t0 = fk * c;
    float e  = fmaf(t0, -99.0f, fk);
    return fmaf(e, c, t0);
}

__device__ __forceinline__ float zq(int k, float dzr, float smin) {
    return fmaf(div99(k), dzr, smin);
}
__device__ __forceinline__ float qat(float z, float trcd, float cam2) {
    return fmaf(z, z + trcd, cam2);
}
// sdf(cam + a*ray) with |ray|=1:  q(a) = a^2 + 2a*rcd + cam2
__device__ __forceinline__ float sdfq(float a, float trcd, float cam2) {
    return fast_sqrtf(fmaxf(qat(a, trcd, cam2), 0.0f)) - 1.0f;
}

// 1 wave per block. Decoupled s/e chains (R10) + EAGER line-search: both
// candidate positions (step and 0.9-backoff) are known before the first sqrt,
// so both sqrts issue in parallel and np selects a finished result — one sqrt
// of dependent latency per iteration instead of two. Decision-exact:
// ns<0 <=> sq<1 (float subtraction is sign-exact), selected values bit-match
// the sequential recompute.
__global__ __launch_bounds__(64) void raytrace_kernel(
    const float* __restrict__ cam, const float* __restrict__ ray,
    float* __restrict__ out, int N, int nshift, int R)
{
    int tid = blockIdx.x * 64 + threadIdx.x;
    bool aliveLane = tid < R;
    int gid = aliveLane ? tid : (R - 1);   // clamp; all 64 lanes live for coop ops
    int lane = threadIdx.x & 63;
    int b = (nshift >= 0) ? (gid >> nshift) : (gid / N);

    float cx = cam[b * 3 + 0], cy = cam[b * 3 + 1], cz = cam[b * 3 + 2];
    float rx = ray[(size_t)gid * 3 + 0], ry = ray[(size_t)gid * 3 + 1], rz = ray[(size_t)gid * 3 + 2];

    float rcd  = rx * cx + ry * cy + rz * cz;
    float cam2 = cx * cx + cy * cy + cz * cz;
    float trcd = rcd + rcd;

    // ---- sphere intersections (OBJ_R = 5); one-time sqrt kept correctly rounded ----
    float under = rcd * rcd - (cam2 - 25.0f);
    bool  m0 = under > 0.0f;
    float sq = sqrtf(m0 ? under : 1.0f);
    float nearv = m0 ? fmaxf(-sq - rcd, 0.0f) : 0.0f;
    float farv  = m0 ? fmaxf( sq - rcd, 0.0f) : 0.0f;

    // ---- decoupled sphere tracing with eager dual-sqrt line search ----
    bool  us = m0, ue = m0;
    float as = nearv, ae = farv;
    float ns = us ? sdfq(as, trcd, cam2) : 0.0f;
    float ne = ue ? sdfq(ae, trcd, cam2) : 0.0f;

    bool  alive = true;                     // joint not-yet-crossed
    float fs = as, fe = ae, fns = ns;       // latched joint state
    bool  ufs = us;

    #pragma unroll 1
    for (int i = 0; i < TRACE_ITERS; ++i) {
        // ---- s-chain ----
        bool  gs = ns > SDF_THR;
        float cs = (us && gs) ? ns : 0.0f;
        us = us && gs;
        float as_step = as + cs;
        float as_back = fmaf(-0.9f, cs, as_step);        // == as_step when cs==0
        float sq_s1 = fast_sqrtf(fmaxf(qat(as_step, trcd, cam2), 0.0f));
        float sq_s2 = fast_sqrtf(fmaxf(qat(as_back, trcd, cam2), 0.0f));  // parallel
        bool np_s = (sq_s1 < 1.0f) || (rcd + as_step > 0.0f);  // ns<0 <=> sq<1 exact
        as = np_s ? as_back : as_step;
        ns = (np_s ? sq_s2 : sq_s1) - 1.0f;
        // ---- e-chain ----
        bool  ge = ne > SDF_THR;
        float ce = (ue && ge) ? ne : 0.0f;
        ue = ue && ge;
        float ae_step = ae - ce;
        float ae_back = fmaf(0.9f, ce, ae_step);
        float sq_e1 = fast_sqrtf(fmaxf(qat(ae_step, trcd, cam2), 0.0f));
        float sq_e2 = fast_sqrtf(fmaxf(qat(ae_back, trcd, cam2), 0.0f));  // parallel
        bool np_e = (sq_e1 < 1.0f) || (rcd + ae_step < 0.0f);
        ae = np_e ? ae_back : ae_step;
        ne = (np_e ? sq_e2 : sq_e1) - 1.0f;
        // ---- joint latch (off-chain) ----
        fs  = alive ? as : fs;
        fe  = alive ? ae : fe;
        fns = alive ? ns : fns;
        ufs = alive ? us : ufs;
        alive = alive && (as < ae);
        bool notdone = alive && (us || ue);
        if (!__any(notdone)) break;          // bit-exact: frozen lanes are no-ops
    }

    // joint final state
    bool unf_s = alive && ufs;
    // final mask refresh
    {
        float curf = unf_s ? fns : 0.0f;
        curf = (curf <= SDF_THR) ? 0.0f : curf;
        unf_s = unf_s && (curf > SDF_THR);
    }

    // ---- defaults from trace ----
    bool  out_m = fs < fe;
    float out_d = fs;

    float smin = fs, dzr = fe - fs;
    int   dec = 1;            // 1 = no-negative (bk_nonneg), 2 = negative (kneg), 0 = fallback
    int   kneg = 1000;
    float bk_nonneg = 0.0f;

    if (unf_s) {
        // ---- analytic sampler: all decisions on computed q(z_k) vs 1 ----
        float step99 = dzr * (1.0f / 99.0f);

        // (a) discrete argmin + any-negative: window around the parabola vertex
        float fkv = (-rcd - smin) / step99;
        fkv = fminf(fmaxf(fkv, 0.0f), 99.0f);
        int kv = (int)fkv;
        float bq = 3.4e38f; float bkf = 0.0f;
        #pragma unroll
        for (int d = -2; d <= 3; ++d) {
            int k = min(max(kv + d, 0), 99);
            float q = qat(zq(k, dzr, smin), trcd, cam2);
            bool better = q < bq;               // strict -> first occurrence
            bq  = better ? q : bq;
            bkf = better ? (float)k : bkf;
        }

        if (fabsf(bq - 1.0f) <= QGUARD) {
            dec = 0;                            // decision inside guard band
        } else if (bq > 1.0f) {
            dec = 1; bk_nonneg = bkf;           // no negative sample anywhere
        } else {
            float q0 = qat(smin, trcd, cam2);   // z_0 == smin exactly
            if (q0 < 1.0f) {
                dec = 2; kneg = 0;
            } else {
                float disc = fmaf(rcd, rcd, 1.0f - cam2);
                float zroot = -rcd - sqrtf(fmaxf(disc, 0.0f));   // left root of q=1
                float fk = (zroot - smin) / step99;
                fk = fminf(fmaxf(fk, -8.0f), 108.0f);
                int ka = (int)ceilf(fk);
                int kw = 1000;
                #pragma unroll
                for (int d = -3; d <= 3; ++d) {
                    int k = min(max(ka + d, 1), 99);
                    float q = qat(zq(k, dzr, smin), trcd, cam2);
                    kw = (q < 1.0f) ? min(kw, k) : kw;
                }
                if (kw == 1000) {
                    dec = 0;                    // analytic index off -> fallback
                } else {
                    float qprev = qat(zq(kw - 1, dzr, smin), trcd, cam2);
                    if (!(qprev >= 1.0f + QGUARD)) dec = 0;   // contiguity unproven
                    else { dec = 2; kneg = kw; }
                }
            }
        }
    }

    // ---- wave-cooperative fallback: full 100-sample scan as a 64-lane reduction ----
    bool need_fb = unf_s && (dec == 0) && aliveLane;
    unsigned long long fbm = __ballot(need_fb);
    while (fbm) {
        int src = __ffsll((unsigned long long)fbm) - 1;
        fbm &= fbm - 1;
        float s_smin = __shfl(smin, src);
        float s_dzr  = __shfl(dzr,  src);
        float s_trcd = __shfl(trcd, src);
        float s_cam2 = __shfl(cam2, src);
        float q1 = qat(zq(lane, s_dzr, s_smin), s_trcd, s_cam2);
        int   k2 = lane + 64;
        bool  v2 = k2 < N_STEPS;
        float q2 = v2 ? qat(zq(k2, s_dzr, s_smin), s_trcd, s_cam2) : 3.4e38f;
        bool b2 = q2 < q1;                      // strict: tie keeps smaller k
        float mq = b2 ? q2 : q1;
        int   mk = b2 ? k2 : lane;
        int nk = 1000;
        nk = (q1 < 1.0f) ? lane : nk;
        nk = (v2 && q2 < 1.0f) ? min(nk, k2) : nk;
        #pragma unroll
        for (int off = 1; off < 64; off <<= 1) {
            float oq = __shfl_xor(mq, off);
            int   ok = __shfl_xor(mk, off);
            int   on = __shfl_xor(nk, off);
            bool bet = (oq < mq) || ((oq == mq) && (ok < mk));
            mq = bet ? oq : mq;
            mk = bet ? ok : mk;
            nk = min(nk, on);
        }
        if (lane == src) {
            if (nk < 1000) { dec = 2; kneg = nk; }
            else           { dec = 1; bk_nonneg = (float)mk; }
        }
    }

    // ---- final resolution (shared bisection for every kneg producer) ----
    if (unf_s) {
        if (dec == 2) {
            int klo = max(kneg - 1, 0);
            float lo = zq(klo,  dzr, smin);     // kneg==0 -> lo==hi==z0 (matches ref)
            float hi = zq(kneg, dzr, smin);
            #pragma unroll
            for (int it = 0; it < N_ROOTFIND; ++it) {
                float mid = 0.5f * (lo + hi);
                float qm  = qat(mid, trcd, cam2);
                bool go_lo = qm > 1.0f;         // sdf(mid) > 0
                lo = go_lo ? mid : lo;
                hi = go_lo ? hi : mid;
            }
            out_d = 0.5f * (lo + hi);
            out_m = true;
        } else {
            out_d = zq((int)bk_nonneg, dzr, smin);   // min-sdf sample
            out_m = false;
        }
    }

    // ---- outputs: pts [R,3] | net_obj [R] | acc_s [R] ----
    if (aliveLane) {
        out[(size_t)gid * 3 + 0] = fmaf(out_d, rx, cx);
        out[(size_t)gid * 3 + 1] = fmaf(out_d, ry, cy);
        out[(size_t)gid * 3 + 2] = fmaf(out_d, rz, cz);
        out[(size_t)R * 3 + gid] = out_m ? 1.0f : 0.0f;
        out[(size_t)R * 4 + gid] = out_d;
    }
}

extern "C" void kernel_launch(void* const* d_in, const int* in_sizes, int n_in,
                              void* d_out, int out_size, void* d_ws, size_t ws_size,
                              hipStream_t stream) {
    const float* cam = (const float*)d_in[0];
    const float* ray = (const float*)d_in[1];
    int B = in_sizes[0] / 3;
    int R = in_sizes[1] / 3;
    int N = R / B;
    int nshift = -1;
    if ((N & (N - 1)) == 0) { nshift = 0; while ((1 << nshift) != N) ++nshift; }
    int threads = 64;
    int blocks = (R + threads - 1) / threads;
    raytrace_kernel<<<blocks, threads, 0, stream>>>(cam, ray, (float*)d_out, N, nshift, R);
}

// Round 12
// 12.417 us; speedup vs baseline: 1.4812x; 1.0651x over previous
//
#include <hip/hip_runtime.h>

#define SDF_THR 5e-5f
#define TRACE_ITERS 10
#define N_STEPS 100
#define N_ROOTFIND 8
#define QGUARD 1e-5f

// raw v_sqrt_f32 (~1 ulp) — avoids the IEEE fixup sequence
__device__ __forceinline__ float fast_sqrtf(float x) {
#if __has_builtin(__builtin_amdgcn_sqrtf)
    return __builtin_amdgcn_sqrtf(x);
#else
    return sqrtf(x);
#endif
}

// correctly-rounded k/99.0f (Markstein 2-fma refinement); same bits whether
// constant-folded (literal k) or evaluated at runtime.
__device__ __forceinline__ float div99(int k) {
    const float c = 1.0f / 99.0f;
    float fk = (float)k;
    float t0 = fk * c;
    float e  = fmaf(t0, -99.0f, fk);
    return fmaf(e, c, t0);
}

__device__ __forceinline__ float zq(int k, float dzr, float smin) {
    return fmaf(div99(k), dzr, smin);
}
__device__ __forceinline__ float qat(float z, float trcd, float cam2) {
    return fmaf(z, z + trcd, cam2);
}
// sdf(cam + a*ray) with |ray|=1:  q(a) = a^2 + 2a*rcd + cam2
__device__ __forceinline__ float sdfq(float a, float trcd, float cam2) {
    return fast_sqrtf(fmaxf(qat(a, trcd, cam2), 0.0f)) - 1.0f;
}

// 1 wave per block. Decoupled s/e chains; ONE sqrt per chain per iteration:
// the line-search decision is made on q (q<1 <=> sdf<0, sign-exact), both
// candidate q's are cheap parallel fmas, and the single sqrt evaluates only
// the SELECTED candidate — bit-identical values, half the transcendental
// issue. fns/ufs latches deleted (provably redundant: unf_s = alive && us,
// and when alive fs==as so fns is recomputable post-loop bit-identically).
__global__ __launch_bounds__(64) void raytrace_kernel(
    const float* __restrict__ cam, const float* __restrict__ ray,
    float* __restrict__ out, int N, int nshift, int R)
{
    int tid = blockIdx.x * 64 + threadIdx.x;
    bool aliveLane = tid < R;
    int gid = aliveLane ? tid : (R - 1);   // clamp; all 64 lanes live for coop ops
    int lane = threadIdx.x & 63;
    int b = (nshift >= 0) ? (gid >> nshift) : (gid / N);
    b = __builtin_amdgcn_readfirstlane(b); // wave-uniform in reality -> scalar loads

    float cx = cam[b * 3 + 0], cy = cam[b * 3 + 1], cz = cam[b * 3 + 2];
    float rx = ray[(size_t)gid * 3 + 0], ry = ray[(size_t)gid * 3 + 1], rz = ray[(size_t)gid * 3 + 2];

    float rcd  = rx * cx + ry * cy + rz * cz;
    float cam2 = cx * cx + cy * cy + cz * cz;
    float trcd = rcd + rcd;

    // ---- sphere intersections (OBJ_R = 5); one-time sqrt kept correctly rounded ----
    float under = rcd * rcd - (cam2 - 25.0f);
    bool  m0 = under > 0.0f;
    float sq = sqrtf(m0 ? under : 1.0f);
    float nearv = m0 ? fmaxf(-sq - rcd, 0.0f) : 0.0f;
    float farv  = m0 ? fmaxf( sq - rcd, 0.0f) : 0.0f;

    // ---- decoupled sphere tracing, 1 sqrt / chain / iter ----
    bool  us = m0, ue = m0;
    float as = nearv, ae = farv;
    float ns = us ? sdfq(as, trcd, cam2) : 0.0f;
    float ne = ue ? sdfq(ae, trcd, cam2) : 0.0f;

    bool  alive = true;                     // joint not-yet-crossed
    float fs = as, fe = ae;                 // latched joint positions

    #pragma unroll 1
    for (int i = 0; i < TRACE_ITERS; ++i) {
        // ---- s-chain ----
        bool  gs = ns > SDF_THR;
        float cs = (us && gs) ? ns : 0.0f;
        us = us && gs;
        float as_step = as + cs;
        float as_back = fmaf(-0.9f, cs, as_step);        // == as_step when cs==0
        float q1s = qat(as_step, trcd, cam2);
        float q2s = qat(as_back, trcd, cam2);            // parallel fma
        bool np_s = (q1s < 1.0f) || (rcd + as_step > 0.0f);  // sdf<0 <=> q<1 exact
        as = np_s ? as_back : as_step;
        float qs = np_s ? q2s : q1s;
        ns = fast_sqrtf(fmaxf(qs, 0.0f)) - 1.0f;         // single sqrt on selected q
        // ---- e-chain ----
        bool  ge = ne > SDF_THR;
        float ce = (ue && ge) ? ne : 0.0f;
        ue = ue && ge;
        float ae_step = ae - ce;
        float ae_back = fmaf(0.9f, ce, ae_step);
        float q1e = qat(ae_step, trcd, cam2);
        float q2e = qat(ae_back, trcd, cam2);            // parallel fma
        bool np_e = (q1e < 1.0f) || (rcd + ae_step < 0.0f);
        ae = np_e ? ae_back : ae_step;
        float qe = np_e ? q2e : q1e;
        ne = fast_sqrtf(fmaxf(qe, 0.0f)) - 1.0f;         // single sqrt on selected q
        // ---- joint latch (positions only) ----
        fs = alive ? as : fs;
        fe = alive ? ae : fe;
        alive = alive && (as < ae);
        bool notdone = alive && (us || ue);
        if (!__any(notdone)) break;          // bit-exact: frozen lanes are no-ops
    }

    // joint final state: unf_s = alive && us (ufs latch provably redundant),
    // fns recomputed bit-identically (when alive, fs == as).
    bool unf_s = alive && us;
    {
        float fns = sdfq(fs, trcd, cam2);
        float curf = unf_s ? fns : 0.0f;
        curf = (curf <= SDF_THR) ? 0.0f : curf;
        unf_s = unf_s && (curf > SDF_THR);
    }

    // ---- defaults from trace ----
    bool  out_m = fs < fe;
    float out_d = fs;

    float smin = fs, dzr = fe - fs;
    int   dec = 1;            // 1 = no-negative (bk_nonneg), 2 = negative (kneg), 0 = fallback
    int   kneg = 1000;
    float bk_nonneg = 0.0f;

    if (unf_s) {
        // ---- analytic sampler: all decisions on computed q(z_k) vs 1 ----
        float step99 = dzr * (1.0f / 99.0f);

        // (a) discrete argmin + any-negative: window around the parabola vertex
        float fkv = (-rcd - smin) / step99;
        fkv = fminf(fmaxf(fkv, 0.0f), 99.0f);
        int kv = (int)fkv;
        float bq = 3.4e38f; float bkf = 0.0f;
        #pragma unroll
        for (int d = -2; d <= 3; ++d) {
            int k = min(max(kv + d, 0), 99);
            float q = qat(zq(k, dzr, smin), trcd, cam2);
            bool better = q < bq;               // strict -> first occurrence
            bq  = better ? q : bq;
            bkf = better ? (float)k : bkf;
        }

        if (fabsf(bq - 1.0f) <= QGUARD) {
            dec = 0;                            // decision inside guard band
        } else if (bq > 1.0f) {
            dec = 1; bk_nonneg = bkf;           // no negative sample anywhere
        } else {
            float q0 = qat(smin, trcd, cam2);   // z_0 == smin exactly
            if (q0 < 1.0f) {
                dec = 2; kneg = 0;
            } else {
                float disc = fmaf(rcd, rcd, 1.0f - cam2);
                float zroot = -rcd - sqrtf(fmaxf(disc, 0.0f));   // left root of q=1
                float fk = (zroot - smin) / step99;
                fk = fminf(fmaxf(fk, -8.0f), 108.0f);
                int ka = (int)ceilf(fk);
                int kw = 1000;
                #pragma unroll
                for (int d = -3; d <= 3; ++d) {
                    int k = min(max(ka + d, 1), 99);
                    float q = qat(zq(k, dzr, smin), trcd, cam2);
                    kw = (q < 1.0f) ? min(kw, k) : kw;
                }
                if (kw == 1000) {
                    dec = 0;                    // analytic index off -> fallback
                } else {
                    float qprev = qat(zq(kw - 1, dzr, smin), trcd, cam2);
                    if (!(qprev >= 1.0f + QGUARD)) dec = 0;   // contiguity unproven
                    else { dec = 2; kneg = kw; }
                }
            }
        }
    }

    // ---- wave-cooperative fallback: full 100-sample scan as a 64-lane reduction ----
    bool need_fb = unf_s && (dec == 0) && aliveLane;
    unsigned long long fbm = __ballot(need_fb);
    while (fbm) {
        int src = __ffsll((unsigned long long)fbm) - 1;
        fbm &= fbm - 1;
        float s_smin = __shfl(smin, src);
        float s_dzr  = __shfl(dzr,  src);
        float s_trcd = __shfl(trcd, src);
        float s_cam2 = __shfl(cam2, src);
        float q1 = qat(zq(lane, s_dzr, s_smin), s_trcd, s_cam2);
        int   k2 = lane + 64;
        bool  v2 = k2 < N_STEPS;
        float q2 = v2 ? qat(zq(k2, s_dzr, s_smin), s_trcd, s_cam2) : 3.4e38f;
        bool b2 = q2 < q1;                      // strict: tie keeps smaller k
        float mq = b2 ? q2 : q1;
        int   mk = b2 ? k2 : lane;
        int nk = 1000;
        nk = (q1 < 1.0f) ? lane : nk;
        nk = (v2 && q2 < 1.0f) ? min(nk, k2) : nk;
        #pragma unroll
        for (int off = 1; off < 64; off <<= 1) {
            float oq = __shfl_xor(mq, off);
            int   ok = __shfl_xor(mk, off);
            int   on = __shfl_xor(nk, off);
            bool bet = (oq < mq) || ((oq == mq) && (ok < mk));
            mq = bet ? oq : mq;
            mk = bet ? ok : mk;
            nk = min(nk, on);
        }
        if (lane == src) {
            if (nk < 1000) { dec = 2; kneg = nk; }
            else           { dec = 1; bk_nonneg = (float)mk; }
        }
    }

    // ---- final resolution (shared bisection for every kneg producer) ----
    if (unf_s) {
        if (dec == 2) {
            int klo = max(kneg - 1, 0);
            float lo = zq(klo,  dzr, smin);     // kneg==0 -> lo==hi==z0 (matches ref)
            float hi = zq(kneg, dzr, smin);
            #pragma unroll
            for (int it = 0; it < N_ROOTFIND; ++it) {
                float mid = 0.5f * (lo + hi);
                float qm  = qat(mid, trcd, cam2);
                bool go_lo = qm > 1.0f;         // sdf(mid) > 0
                lo = go_lo ? mid : lo;
                hi = go_lo ? hi : mid;
            }
            out_d = 0.5f * (lo + hi);
            out_m = true;
        } else {
            out_d = zq((int)bk_nonneg, dzr, smin);   // min-sdf sample
            out_m = false;
        }
    }

    // ---- outputs: pts [R,3] | net_obj [R] | acc_s [R] ----
    if (aliveLane) {
        out[(size_t)gid * 3 + 0] = fmaf(out_d, rx, cx);
        out[(size_t)gid * 3 + 1] = fmaf(out_d, ry, cy);
        out[(size_t)gid * 3 + 2] = fmaf(out_d, rz, cz);
        out[(size_t)R * 3 + gid] = out_m ? 1.0f : 0.0f;
        out[(size_t)R * 4 + gid] = out_d;
    }
}

extern "C" void kernel_launch(void* const* d_in, const int* in_sizes, int n_in,
                              void* d_out, int out_size, void* d_ws, size_t ws_size,
                              hipStream_t stream) {
    const float* cam = (const float*)d_in[0];
    const float* ray = (const float*)d_in[1];
    int B = in_sizes[0] / 3;
    int R = in_sizes[1] / 3;
    int N = R / B;
    int nshift = -1;
    if ((N & (N - 1)) == 0) { nshift = 0; while ((1 << nshift) != N) ++nshift; }
    int threads = 64;
    int blocks = (R + threads - 1) / threads;
    raytrace_kernel<<<blocks, threads, 0, stream>>>(cam, ray, (float*)d_out, N, nshift, R);
}